// Round 10
// baseline (405.411 us; speedup 1.0000x reference)
//
#include <hip/hip_runtime.h>
#include <hip/hip_bf16.h>

#define LSEQ 2048
#define DMODEL 2048
#define DINNER 4096
#define DSTATE 16
#define DTRANK 128
#define DCONV 4
#define DXP (DTRANK + 2*DSTATE)   // 160
#define NCHUNK 32
#define LCHUNK (LSEQ / NCHUNK)    // 64
#define KSPLIT 16

using bf16 = __hip_bfloat16;
typedef __attribute__((ext_vector_type(8))) short short8;
typedef __attribute__((ext_vector_type(4))) float float4v;

__device__ __forceinline__ float b2f(bf16 v) { return __bfloat162float(v); }
__device__ __forceinline__ bf16 f2b(float v) { return __float2bfloat16(v); }
__device__ __forceinline__ float bl16(unsigned u) { return __uint_as_float(u << 16); }
__device__ __forceinline__ float bh16(unsigned u) { return __uint_as_float(u & 0xffff0000u); }

__device__ __forceinline__ short f2bs(float v) {
    bf16 b = __float2bfloat16(v);
    union { bf16 b; short s; } u; u.b = b; return u.s;
}

// fast silu: x * sigmoid(x) with v_rcp instead of full-precision divide
__device__ __forceinline__ float fsilu(float x) {
    return x * __builtin_amdgcn_rcpf(1.0f + __expf(-x));
}

__device__ __forceinline__ short8 ld8(const float* p) {
    float4v f0 = *(const float4v*)p;
    float4v f1 = *(const float4v*)(p + 4);
    short8 r;
    r[0] = f2bs(f0[0]); r[1] = f2bs(f0[1]); r[2] = f2bs(f0[2]); r[3] = f2bs(f0[3]);
    r[4] = f2bs(f1[0]); r[5] = f2bs(f1[1]); r[6] = f2bs(f1[2]); r[7] = f2bs(f1[3]);
    return r;
}
__device__ __forceinline__ short8 ld8(const bf16* p) { return *(const short8*)p; }

template<typename CT> __device__ __forceinline__ CT cvtC(float v);
template<> __device__ __forceinline__ bf16  cvtC<bf16>(float v)  { return f2b(v); }
template<> __device__ __forceinline__ float cvtC<float>(float v) { return v; }

template<typename T> __device__ __forceinline__ float cvtL(T v);
template<> __device__ __forceinline__ float cvtL<bf16>(bf16 v)   { return b2f(v); }
template<> __device__ __forceinline__ float cvtL<float>(float v) { return v; }

// async global->LDS, 16 B per lane, dest = wave-uniform base + lane*16
__device__ __forceinline__ void glds16(const bf16* g, void* lds_base) {
    __builtin_amdgcn_global_load_lds(
        (const __attribute__((address_space(1))) void*)g,
        (__attribute__((address_space(3))) void*)lds_base, 16, 0, 0);
}

// ---- fused fp32->bf16 convert of four arrays (each n % 2048 == 0) ----
__global__ __launch_bounds__(256) void cvt4(
    const float* __restrict__ s0, bf16* __restrict__ d0, int n0,
    const float* __restrict__ s1, bf16* __restrict__ d1, int n1,
    const float* __restrict__ s2, bf16* __restrict__ d2, int n2,
    const float* __restrict__ s3, bf16* __restrict__ d3, int n3)
{
    const int b = blockIdx.x;
    const int nb0 = n0 >> 11, nb1 = n1 >> 11, nb2 = n2 >> 11;
    const float* s; bf16* d; int i;
    if (b < nb0)                  { s = s0; d = d0; i = b * 2048; }
    else if (b < nb0 + nb1)       { s = s1; d = d1; i = (b - nb0) * 2048; }
    else if (b < nb0 + nb1 + nb2) { s = s2; d = d2; i = (b - nb0 - nb1) * 2048; }
    else                          { s = s3; d = d3; i = (b - nb0 - nb1 - nb2) * 2048; }
    i += threadIdx.x * 8;
    *(short8*)(d + i) = ld8(s + i);
}

__global__ __launch_bounds__(256) void cvt1(
    const float* __restrict__ src, bf16* __restrict__ dst, int n)
{
    int i = (blockIdx.x * 256 + threadIdx.x) * 8;
    if (i >= n) return;
    *(short8*)(dst + i) = ld8(src + i);
}

// ============================================================================
// 256x256 2-phase/tile pipelined GEMM (in_proj). ONE trailing barrier per
// phase, 2 phases per K-tile (was 4 - R2->R3 showed halving barriers = -11us).
// Region schedule (counted vmcnt, never 0 mid-loop):
//   phase A: compute (Alo x Blo) + (Alo x Bhi), 32 MFMA;
//            stage (T+1).AHi+BLo+BHi (other buffer, occupant died T-1.B)
//   phase B: compute (Ahi x Bhi) + (Ahi x Blo), 32 MFMA;
//            stage (T+2).ALo (current buffer; ALo last read in phase A,
//            fenced by A's trailing barrier)
//   end of T.B: in-flight = (T+1).ALo[2] + T.A's 6 + T.B's 2 = 10
//               -> vmcnt(2) drains exactly all of tile T+1.
// ============================================================================
#define GBAR  __builtin_amdgcn_s_barrier()
#define VMW2  asm volatile("s_waitcnt vmcnt(2)" ::: "memory")
#define VMW8  asm volatile("s_waitcnt vmcnt(8)" ::: "memory")
#define VMW0  asm volatile("s_waitcnt vmcnt(0)" ::: "memory")

#define LDA8(BASE, RB, AF) do {                                                \
  _Pragma("unroll") for (int mi_ = 0; mi_ < 4; ++mi_)                          \
  _Pragma("unroll") for (int kk_ = 0; kk_ < 2; ++kk_)                          \
    AF[mi_][kk_] = *(const short8*)((BASE) + (((RB) + mi_*16 + t16) << 6)      \
                                    + ((((kk_*4) + quad) ^ sw7) << 3));        \
} while (0)

#define LDB4(BASE, RB, BF) do {                                                \
  _Pragma("unroll") for (int nj_ = 0; nj_ < 2; ++nj_)                          \
  _Pragma("unroll") for (int kk_ = 0; kk_ < 2; ++kk_)                          \
    BF[nj_][kk_] = *(const short8*)((BASE) + (((RB) + nj_*16 + t16) << 6)      \
                                    + ((((kk_*4) + quad) ^ sw7) << 3));        \
} while (0)

#define MM16(AF, BF, MO, NO) do {                                              \
  _Pragma("unroll") for (int kk_ = 0; kk_ < 2; ++kk_)                          \
  _Pragma("unroll") for (int mi_ = 0; mi_ < 4; ++mi_)                          \
  _Pragma("unroll") for (int nj_ = 0; nj_ < 2; ++nj_)                          \
    acc[(MO)+mi_][(NO)+nj_] = __builtin_amdgcn_mfma_f32_16x16x32_bf16(         \
        AF[mi_][kk_], BF[nj_][kk_], acc[(MO)+mi_][(NO)+nj_], 0, 0, 0);         \
} while (0)

#define ST_ALO(tau) do { size_t ko_ = (size_t)(tau) << 6; int bo_ = ((tau)&1) << 15; \
  glds16(sA +       ko_, dA0 + bo_);                                           \
  glds16(sA + oA1 + ko_, dA1 + bo_); } while (0)
#define ST_AHI(tau) do { size_t ko_ = (size_t)(tau) << 6; int bo_ = ((tau)&1) << 15; \
  glds16(sA + oA2 + ko_, dA2 + bo_);                                           \
  glds16(sA + oA3 + ko_, dA3 + bo_); } while (0)
#define ST_BLO(tau) do { size_t ko_ = (size_t)(tau) << 6; int bo_ = ((tau)&1) << 15; \
  glds16(sB +       ko_, dB0 + bo_);                                           \
  glds16(sB + oB1 + ko_, dB1 + bo_); } while (0)
#define ST_BHI(tau) do { size_t ko_ = (size_t)(tau) << 6; int bo_ = ((tau)&1) << 15; \
  glds16(sB + oB2 + ko_, dB2 + bo_);                                           \
  glds16(sB + oB3 + ko_, dB3 + bo_); } while (0)

// one K-tile (2 phases), BI = compile-time buffer index
#define KSTEP(T, BI) do {                                                      \
    const bf16* Ab = As[BI];                                                   \
    const bf16* Bb = Bs[BI];                                                   \
    short8 af[4][2], b0[2][2], b1[2][2];                                       \
    /* phase A: (Alo x Blo)+(Alo x Bhi); stage (T+1).AHi+BLo+BHi */            \
    LDA8(Ab, wm, af);                                                          \
    LDB4(Bb, wn, b0);                                                          \
    LDB4(Bb, wn + 32, b1);                                                     \
    if ((T) + 1 < NT) { ST_AHI((T) + 1); ST_BLO((T) + 1); ST_BHI((T) + 1); }   \
    __builtin_amdgcn_s_setprio(1);                                             \
    MM16(af, b0, 0, 0); MM16(af, b1, 0, 2);                                    \
    __builtin_amdgcn_s_setprio(0); GBAR;                                       \
    /* phase B: (Ahi x Bhi)+(Ahi x Blo); stage (T+2).ALo */                    \
    LDA8(Ab, wm + 64, af);                                                     \
    if ((T) + 2 < NT) ST_ALO((T) + 2);                                         \
    __builtin_amdgcn_s_setprio(1);                                             \
    MM16(af, b1, 4, 2); MM16(af, b0, 4, 0);                                    \
    __builtin_amdgcn_s_setprio(0);                                             \
    if ((T) + 2 < NT) { VMW2; } else { VMW0; }                                 \
    GBAR;                                                                      \
} while (0)

#define GEMM_PRO_COMMON                                                        \
    const int t    = threadIdx.x;                                              \
    const int wave = t >> 6;                                                   \
    const int lane = t & 63;                                                   \
    const int t16  = lane & 15;                                                \
    const int quad = lane >> 4;                                                \
    const int sw7  = t16 & 7;                                                  \
    const int wm   = (wave >> 2) * 128;                                        \
    const int wn   = (wave & 3) * 64;                                          \
    const int lrow  = lane >> 3;                                               \
    const int lseg  = lane & 7;                                                \
    const int segx  = (lseg ^ lrow) * 8;                                       \
    const int bwoff = (wave & 3) * 8 + (wave >> 2) * 64;

#define GEMM_LDS_DSTS                                                          \
    char* dA0 = (char*)&As[0][(  0 + wave * 8) * 64];                          \
    char* dA1 = (char*)&As[0][(128 + wave * 8) * 64];                          \
    char* dA2 = (char*)&As[0][( 64 + wave * 8) * 64];                          \
    char* dA3 = (char*)&As[0][(192 + wave * 8) * 64];                          \
    char* dB0 = (char*)&Bs[0][(  0 + bwoff) * 64];                             \
    char* dB1 = (char*)&Bs[0][(128 + bwoff) * 64];                             \
    char* dB2 = (char*)&Bs[0][( 32 + bwoff) * 64];                             \
    char* dB3 = (char*)&Bs[0][(160 + bwoff) * 64];

// ---- in_proj: M=2048 (8 tiles) x N (32 tiles), grid 256, bf16 C ----
__global__ __launch_bounds__(512, 2) void gemm_inproj(
    const bf16* __restrict__ A, int lda,
    const bf16* __restrict__ B, int ldb,
    bf16* __restrict__ C, int ldc, int K)
{
    __shared__ __align__(16) bf16 As[2][256 * 64];
    __shared__ __align__(16) bf16 Bs[2][256 * 64];
    GEMM_PRO_COMMON
    const int bid = blockIdx.x;
    const int s   = (bid & 7) * (gridDim.x >> 3) + (bid >> 3);
    const int bm0 = (s & 7) << 8;
    const int bn0 = (s >> 3) << 8;

    const bf16* sA = A + (size_t)(bm0 + wave * 8 + lrow) * lda + segx;
    const bf16* sB = B + (size_t)(bn0 + bwoff + lrow) * ldb + segx;
    const size_t oA1 = (size_t)128 * lda, oA2 = (size_t)64 * lda, oA3 = (size_t)192 * lda;
    const size_t oB1 = (size_t)128 * ldb, oB2 = (size_t)32 * ldb, oB3 = (size_t)160 * ldb;
    GEMM_LDS_DSTS

    const int NT = K >> 6;   // must be even, >= 2

    float4v acc[8][4];
#pragma unroll
    for (int i = 0; i < 8; ++i)
#pragma unroll
        for (int j = 0; j < 4; ++j) acc[i][j] = (float4v)(0.0f);

    // prologue: tile0 fully (8 glds) + tile1.ALo (2); drain tile0 -> vmcnt(2)
    ST_ALO(0); ST_AHI(0); ST_BLO(0); ST_BHI(0);
    if (NT > 1) { ST_ALO(1); VMW2; } else { VMW0; }
    GBAR;

    for (int T = 0; T < NT; T += 2) {
        KSTEP(T, 0);
        KSTEP(T + 1, 1);
    }

#pragma unroll
    for (int mi = 0; mi < 8; ++mi) {
#pragma unroll
        for (int nj = 0; nj < 4; ++nj) {
            const int m_base = bm0 + wm + (mi >> 2) * 64 + (mi & 3) * 16 + quad * 4;
            const int n_g    = bn0 + wn + (nj >> 1) * 32 + (nj & 1) * 16 + t16;
#pragma unroll
            for (int r = 0; r < 4; ++r)
                C[(size_t)(m_base + r) * ldc + n_g] = f2b(acc[mi][nj][r]);
        }
    }
}

// ============================================================================
// out_proj: single-pass 128x128-tile PIPELINED GEMM. 256 blocks (1/CU),
// triple-buffered LDS (96 KB), stage T+2 during T, one trailing barrier per
// K-tile, counted vmcnt(8). REQUIRES: NT % 3 == 1 (K=4096 -> NT=64).
// ============================================================================
#define OST(tau, BI) do { size_t ko_ = (size_t)(tau) << 6;                     \
  _Pragma("unroll") for (int g_ = 0; g_ < 4; ++g_) {                           \
    glds16(Ag[g_] + ko_, Ad[g_] + (BI) * 16384);                               \
    glds16(Bg[g_] + ko_, Bd[g_] + (BI) * 16384); } } while (0)

#define OKSTEP(T, BI) do {                                                     \
    const bf16* Ab = &As[BI][0];                                               \
    const bf16* Bb = &Bs[BI][0];                                               \
    short8 a_[4][2], b_[4][2];                                                 \
    _Pragma("unroll") for (int mi_ = 0; mi_ < 4; ++mi_)                        \
    _Pragma("unroll") for (int kk_ = 0; kk_ < 2; ++kk_)                        \
      a_[mi_][kk_] = *(const short8*)(Ab + ((wm + mi_*16 + t16) << 6)          \
                                      + ((((kk_*4) + quad) ^ sw) << 3));       \
    _Pragma("unroll") for (int nj_ = 0; nj_ < 4; ++nj_)                        \
    _Pragma("unroll") for (int kk_ = 0; kk_ < 2; ++kk_)                        \
      b_[nj_][kk_] = *(const short8*)(Bb + ((wn + nj_*16 + t16) << 6)          \
                                      + ((((kk_*4) + quad) ^ sw) << 3));       \
    if ((T) + 2 < NT) OST((T) + 2, ((BI) + 2) % 3);                            \
    __builtin_amdgcn_s_setprio(1);                                             \
    _Pragma("unroll") for (int kk_ = 0; kk_ < 2; ++kk_)                        \
    _Pragma("unroll") for (int mi_ = 0; mi_ < 4; ++mi_)                        \
    _Pragma("unroll") for (int nj_ = 0; nj_ < 4; ++nj_)                        \
      acc[mi_][nj_] = __builtin_amdgcn_mfma_f32_16x16x32_bf16(                 \
          a_[mi_][kk_], b_[nj_][kk_], acc[mi_][nj_], 0, 0, 0);                 \
    __builtin_amdgcn_s_setprio(0);                                             \
    if ((T) + 2 < NT) { VMW8; }                                                \
    else if ((T) + 1 < NT) { VMW0; }                                           \
    GBAR;                                                                      \
} while (0)

__global__ __launch_bounds__(256, 1) void gemm_outproj(
    const bf16* __restrict__ A, int lda,
    const bf16* __restrict__ B, int ldb,
    float* __restrict__ C, int ldc, int K)
{
    __shared__ __align__(16) bf16 As[3][128 * 64];   // 48 KB
    __shared__ __align__(16) bf16 Bs[3][128 * 64];   // 48 KB

    const int t    = threadIdx.x;
    const int wave = t >> 6;
    const int lane = t & 63;
    const int t16  = lane & 15;
    const int quad = lane >> 4;
    const int sw   = t16 & 7;
    const int wm   = (wave >> 1) * 64;
    const int wn   = (wave & 1) * 64;

    // XCD-region swizzle: each XCD owns an 8m x 4n tile region (bijective)
    const int bid = blockIdx.x;
    const int m_t = ((bid & 1) << 3) | ((bid >> 3) & 7);
    const int n_t = (((bid >> 1) & 3) << 2) | ((bid >> 6) & 3);
    const int bm0 = m_t << 7;
    const int bn0 = n_t << 7;

    const int lrow = lane >> 3;
    const int gseg = ((lane & 7) ^ lrow) * 8;

    const bf16* Ag[4]; char* Ad[4];
#pragma unroll
    for (int g = 0; g < 4; g++) {
        int r = wave * 32 + g * 8;
        Ag[g] = A + (size_t)(bm0 + r + lrow) * lda + gseg;
        Ad[g] = (char*)&As[0][0] + r * 128;
    }
    const bf16* Bg[4]; char* Bd[4];
#pragma unroll
    for (int g = 0; g < 4; g++) {
        int r = wave * 32 + g * 8;
        Bg[g] = B + (size_t)(bn0 + r + lrow) * ldb + gseg;
        Bd[g] = (char*)&Bs[0][0] + r * 128;
    }

    const int NT = K >> 6;   // must satisfy NT % 3 == 1, NT >= 4

    float4v acc[4][4];
#pragma unroll
    for (int i = 0; i < 4; i++)
#pragma unroll
        for (int j = 0; j < 4; j++) acc[i][j] = (float4v)(0.0f);

    OST(0, 0);
    OST(1, 1);
    VMW8;
    GBAR;

    for (int T = 0; T + 2 < NT; T += 3) {
        OKSTEP(T, 0);
        OKSTEP(T + 1, 1);
        OKSTEP(T + 2, 2);
    }
    OKSTEP(NT - 1, 0);   // NT % 3 == 1 -> (NT-1) % 3 == 0

#pragma unroll
    for (int mi = 0; mi < 4; mi++) {
#pragma unroll
        for (int nj = 0; nj < 4; nj++) {
            int n_g = bn0 + wn + nj * 16 + t16;
#pragma unroll
            for (int r = 0; r < 4; r++) {
                int m_g = bm0 + wm + mi * 16 + quad * 4 + r;
                C[(size_t)m_g * ldc + n_g] = acc[mi][nj][r];
            }
        }
    }
}

// ============================================================================
// Dedicated x_proj GEMM: M=2048 (16 tiles of 128) x N=160, split-K=16.
// ============================================================================
__global__ __launch_bounds__(256) void gemm_xproj(
    const bf16* __restrict__ A, int lda,      // xc [2048][4096]
    const bf16* __restrict__ B, int ldb,      // w_xproj_b [160][4096]
    float* __restrict__ P)                    // [KSPLIT][2048][160]
{
    __shared__ bf16 As[128][64];              // 16 KB
    __shared__ bf16 Bs[160][64];              // 20 KB

    const int t    = threadIdx.x;
    const int wave = t >> 6;
    const int lane = t & 63;
    const int t16  = lane & 15;
    const int quad = lane >> 4;
    const int wm   = (wave >> 1) * 64;
    const int wn   = (wave & 1) * 80;
    const int bm0  = blockIdx.x * 128;
    const int kbeg = blockIdx.y * (DINNER / KSPLIT);   // 256-wide K slice

    const int lrow = lane >> 3;
    const int gseg = ((lane & 7) ^ lrow) * 8;

    const bf16* Ag[4]; char* Ad[4];
#pragma unroll
    for (int g = 0; g < 4; g++) {
        int r = wave * 32 + g * 8;
        Ag[g] = A + (size_t)(bm0 + r + lrow) * lda + gseg + kbeg;
        Ad[g] = (char*)As + r * 128;
    }
    const bf16* Bg[5]; char* Bd[5];
#pragma unroll
    for (int g = 0; g < 5; g++) {
        int r = wave * 40 + g * 8;
        Bg[g] = B + (size_t)(r + lrow) * ldb + gseg + kbeg;
        Bd[g] = (char*)Bs + r * 128;
    }

    float4v acc[4][5];
#pragma unroll
    for (int i = 0; i < 4; i++)
#pragma unroll
        for (int j = 0; j < 5; j++) acc[i][j] = (float4v)(0.0f);

    const int sw = t16 & 7;

    for (int k0 = 0; k0 < DINNER / KSPLIT; k0 += 64) {
        __syncthreads();
#pragma unroll
        for (int g = 0; g < 4; g++) glds16(Ag[g] + k0, Ad[g]);
#pragma unroll
        for (int g = 0; g < 5; g++) glds16(Bg[g] + k0, Bd[g]);
        __syncthreads();

#pragma unroll
        for (int kk = 0; kk < 2; kk++) {
            const int kso = ((kk * 4 + quad) ^ sw) * 8;
            short8 a[4], b[5];
#pragma unroll
            for (int mi = 0; mi < 4; mi++)
                a[mi] = *(const short8*)(&As[wm + mi * 16 + t16][kso]);
#pragma unroll
            for (int nj = 0; nj < 5; nj++)
                b[nj] = *(const short8*)(&Bs[wn + nj * 16 + t16][kso]);
#pragma unroll
            for (int mi = 0; mi < 4; mi++)
#pragma unroll
                for (int nj = 0; nj < 5; nj++)
                    acc[mi][nj] = __builtin_amdgcn_mfma_f32_16x16x32_bf16(
                        a[mi], b[nj], acc[mi][nj], 0, 0, 0);
        }
    }

    float* Pk = P + (size_t)blockIdx.y * LSEQ * DXP;
#pragma unroll
    for (int mi = 0; mi < 4; mi++) {
#pragma unroll
        for (int nj = 0; nj < 5; nj++) {
            int n_g = wn + nj * 16 + t16;
#pragma unroll
            for (int r = 0; r < 4; r++) {
                int m_g = bm0 + wm + mi * 16 + quad * 4 + r;
                Pk[(size_t)m_g * DXP + n_g] = acc[mi][nj][r];
            }
        }
    }
}

// ============================================================================
// Dedicated dt_proj: single-stage K=128 GEMM + bias + softplus -> fp32.
// A = xdbl [2048][160] (cols 0..127), B = w_dt_b [4096][128].
// Tile 128x128, grid (16,32), 64 KB LDS (2 blocks/CU), ONE barrier pair.
// 256-B LDS rows with 16-segment XOR swizzle (2-way bank alias = free).
// ============================================================================
__global__ __launch_bounds__(256) void gemm_dtproj(
    const bf16* __restrict__ A,
    const bf16* __restrict__ B,
    float* __restrict__ C,
    const float* __restrict__ bias)
{
    __shared__ __align__(16) bf16 As[128][128];   // 32 KB
    __shared__ __align__(16) bf16 Bs[128][128];   // 32 KB

    const int t    = threadIdx.x;
    const int wave = t >> 6;
    const int lane = t & 63;
    const int t16  = lane & 15;
    const int quad = lane >> 4;
    const int wm   = (wave >> 1) * 64;
    const int wn   = (wave & 1) * 64;
    const int bm0  = blockIdx.x * 128;
    const int bn0  = blockIdx.y * 128;

    // per statement: 256 thr x 16B = 16 rows of 256B; wave covers 4 rows
    const int srow = wave * 4 + (lane >> 4);          // row-in-group 0..15
    const int scol = ((lane & 15) ^ srow) * 8;        // pre-swizzled col (elems)

    // stage all of K=128: 8 A statements + 8 B statements
#pragma unroll
    for (int g = 0; g < 8; g++) {
        glds16(A + (size_t)(bm0 + g * 16 + srow) * DXP + scol,
               (char*)As + (g * 16 + wave * 4) * 256);
        glds16(B + (size_t)(bn0 + g * 16 + srow) * DTRANK + scol,
               (char*)Bs + (g * 16 + wave * 4) * 256);
    }
    VMW0;
    GBAR;

    float4v acc[4][4];
#pragma unroll
    for (int i = 0; i < 4; i++)
#pragma unroll
        for (int j = 0; j < 4; j++) acc[i][j] = (float4v)(0.0f);

#pragma unroll
    for (int kk = 0; kk < 4; kk++) {
        const int kso = ((kk * 4 + quad) ^ t16) * 8;
        short8 a[4], b[4];
#pragma unroll
        for (int mi = 0; mi < 4; mi++)
            a[mi] = *(const short8*)(&As[wm + mi * 16 + t16][kso]);
#pragma unroll
        for (int nj = 0; nj < 4; nj++)
            b[nj] = *(const short8*)(&Bs[wn + nj * 16 + t16][kso]);
#pragma unroll
        for (int mi = 0; mi < 4; mi++)
#pragma unroll
            for (int nj = 0; nj < 4; nj++)
                acc[mi][nj] = __builtin_amdgcn_mfma_f32_16x16x32_bf16(
                    a[mi], b[nj], acc[mi][nj], 0, 0, 0);
    }

#pragma unroll
    for (int mi = 0; mi < 4; mi++) {
#pragma unroll
        for (int nj = 0; nj < 4; nj++) {
            int n_g = bn0 + wn + nj * 16 + t16;
            float bia = bias[n_g];
#pragma unroll
            for (int r = 0; r < 4; r++) {
                int m_g = bm0 + wm + mi * 16 + quad * 4 + r;
                float x = acc[mi][nj][r] + bia;
                float v = (x > 20.0f) ? x : __logf(1.0f + __expf(x));
                C[(size_t)m_g * DINNER + n_g] = v;
            }
        }
    }
}

// ---- guarded 64x64 GEMM (fallback tiers); B is fp32 ----
template<typename AT, typename CT, bool SP>
__global__ __launch_bounds__(256) void gemm_bt(
    const AT* __restrict__ A, int lda,
    const float* __restrict__ B, int ldb,
    CT* __restrict__ C, int ldc,
    int M, int N, int K,
    const float* __restrict__ bias)
{
    __shared__ bf16 As[64][40];
    __shared__ bf16 Bs[64][40];

    const int t    = threadIdx.x;
    const int bm0  = blockIdx.x * 64;
    const int bn0  = blockIdx.y * 64;
    const int row  = t >> 2;
    const int seg  = (t & 3) * 8;
    const int wave = t >> 6;
    const int lane = t & 63;
    const int wm   = (wave >> 1) * 32;
    const int wn   = (wave & 1) * 32;
    const int t16  = lane & 15;
    const int quad = lane >> 4;

    float4v acc[2][2];
#pragma unroll
    for (int i = 0; i < 2; i++)
#pragma unroll
        for (int j = 0; j < 2; j++) acc[i][j] = (float4v)(0.0f);

    const AT*    Aptr = A + (size_t)(bm0 + row) * lda + seg;
    const float* Bptr = B + (size_t)(bn0 + row) * ldb + seg;
    const bool a_ok = (bm0 + row) < M;
    const bool b_ok = (bn0 + row) < N;
    const short8 zero8 = (short8)(0);

    for (int k0 = 0; k0 < K; k0 += 32) {
        short8 av = a_ok ? ld8(Aptr + k0) : zero8;
        short8 bv = b_ok ? ld8(Bptr + k0) : zero8;
        __syncthreads();
        *(short8*)(&As[row][seg]) = av;
        *(short8*)(&Bs[row][seg]) = bv;
        __syncthreads();

        short8 a0 = *(const short8*)(&As[wm + t16][quad * 8]);
        short8 a1 = *(const short8*)(&As[wm + 16 + t16][quad * 8]);
        short8 b0 = *(const short8*)(&Bs[wn + t16][quad * 8]);
        short8 b1 = *(const short8*)(&Bs[wn + 16 + t16][quad * 8]);
        acc[0][0] = __builtin_amdgcn_mfma_f32_16x16x32_bf16(a0, b0, acc[0][0], 0, 0, 0);
        acc[0][1] = __builtin_amdgcn_mfma_f32_16x16x32_bf16(a0, b1, acc[0][1], 0, 0, 0);
        acc[1][0] = __builtin_amdgcn_mfma_f32_16x16x32_bf16(a1, b0, acc[1][0], 0, 0, 0);
        acc[1][1] = __builtin_amdgcn_mfma_f32_16x16x32_bf16(a1, b1, acc[1][1], 0, 0, 0);
    }

#pragma unroll
    for (int i = 0; i < 2; i++) {
#pragma unroll
        for (int j = 0; j < 2; j++) {
            int n_g = bn0 + wn + j * 16 + t16;
            if (n_g >= N) continue;
            float bia = SP ? bias[n_g] : 0.0f;
#pragma unroll
            for (int r = 0; r < 4; r++) {
                int m_g = bm0 + wm + i * 16 + quad * 4 + r;
                if (m_g >= M) continue;
                float v = acc[i][j][r];
                if (SP) {
                    float x = v + bia;
                    v = (x > 20.0f) ? x : log1pf(__expf(x));
                }
                C[(size_t)m_g * ldc + n_g] = cvtC<CT>(v);
            }
        }
    }
}

// ---- sum KS fp32 partials -> bf16 xdbl; also emit fp32 B/C side-buffer ----
// bc layout: [l][32] fp32 : B[0..15], C[0..15]  (256 KB, L2-resident)
__global__ __launch_bounds__(256) void reduce_splitk(
    const float* __restrict__ P, bf16* __restrict__ C, float* __restrict__ bc, int MN)
{
    int i = blockIdx.x * 256 + threadIdx.x;
    if (i >= MN) return;
    float s = 0.f;
#pragma unroll
    for (int ks = 0; ks < KSPLIT; ks++) s += P[(size_t)ks * MN + i];
    C[i] = f2b(s);
    int l = i / DXP;
    int p = i - l * DXP;
    if (p >= DTRANK) bc[l * 32 + (p - DTRANK)] = s;
}

// ---- conv, L-parallel: reads xz (x-half), writes xc; 64 l per block ----
__global__ __launch_bounds__(256) void conv_silu_par(
    const bf16* __restrict__ xz, const float* __restrict__ w, bf16* __restrict__ xc)
{
    const int d  = blockIdx.x * 256 + threadIdx.x;
    const int lc = blockIdx.y * 64;
    const float w0 = w[d * 4 + 0];
    const float w1 = w[d * 4 + 1];
    const float w2 = w[d * 4 + 2];
    const float w3 = w[d * 4 + 3];
    const size_t S = 2 * DINNER;
    const bf16* p = xz + d;
    float xm3 = 0.f, xm2 = 0.f, xm1 = 0.f;
    if (lc >= 3) {
        xm3 = b2f(p[(size_t)(lc - 3) * S]);
        xm2 = b2f(p[(size_t)(lc - 2) * S]);
        xm1 = b2f(p[(size_t)(lc - 1) * S]);
    }
    for (int l = lc; l < lc + 64; ++l) {
        float x0 = b2f(p[(size_t)l * S]);
        float a = w0 * xm3 + w1 * xm2 + w2 * xm1 + w3 * x0;
        xc[(size_t)l * DINNER + d] = f2b(fsilu(a));
        xm3 = xm2; xm2 = xm1; xm1 = x0;
    }
}

// ---- conv, serial in-place fallback ----
__global__ __launch_bounds__(256) void conv_silu_inplace(
    bf16* __restrict__ xz, const float* __restrict__ w)
{
    const int d = blockIdx.x * 256 + threadIdx.x;
    const float w0 = w[d * 4 + 0];
    const float w1 = w[d * 4 + 1];
    const float w2 = w[d * 4 + 2];
    const float w3 = w[d * 4 + 3];
    bf16* p = xz + d;
    const size_t S = 2 * DINNER;
    float xm3 = 0.f, xm2 = 0.f, xm1 = 0.f;
    for (int l = 0; l < LSEQ; l += 4) {
        float x0 = b2f(p[(size_t)(l + 0) * S]);
        float x1 = b2f(p[(size_t)(l + 1) * S]);
        float x2 = b2f(p[(size_t)(l + 2) * S]);
        float x3 = b2f(p[(size_t)(l + 3) * S]);
        float a0 = w0 * xm3 + w1 * xm2 + w2 * xm1 + w3 * x0;
        float a1 = w0 * xm2 + w1 * xm1 + w2 * x0  + w3 * x1;
        float a2 = w0 * xm1 + w1 * x0  + w2 * x1  + w3 * x2;
        float a3 = w0 * x0  + w1 * x1  + w2 * x2  + w3 * x3;
        p[(size_t)(l + 0) * S] = f2b(a0 / (1.0f + __expf(-a0)));
        p[(size_t)(l + 1) * S] = f2b(a1 / (1.0f + __expf(-a1)));
        p[(size_t)(l + 2) * S] = f2b(a2 / (1.0f + __expf(-a2)));
        p[(size_t)(l + 3) * S] = f2b(a3 / (1.0f + __expf(-a3)));
        xm3 = x1; xm2 = x2; xm1 = x3;
    }
}

// ============================================================================
// Chunked scan v3: ONE lane per d, all 16 states in-register. __expf (native
// v_exp path) — exp2f regressed ~20us (precise libm, R8 post-mortem).
// NCHUNK=32 (LCHUNK=64): halves hend/Pbuf traffic + combine chain.
// ============================================================================
__global__ __launch_bounds__(256) void scan_chunk1(
    const float* __restrict__ dlt, const bf16* __restrict__ xc,
    const float* __restrict__ bc, const float* __restrict__ A_log,
    float* __restrict__ hend, float* __restrict__ Pbuf)
{
    const int d = blockIdx.x * 256 + threadIdx.x;
    const int c = blockIdx.y;

    float Ac[16];
    {
        const float* ap = A_log + d * DSTATE;
#pragma unroll
        for (int i = 0; i < 16; i++) Ac[i] = -__expf(ap[i]);
    }

    float h[16];
#pragma unroll
    for (int i = 0; i < 16; i++) h[i] = 0.f;
    float sdelta = 0.f;

    const float* pd = dlt + (size_t)c * LCHUNK * DINNER + d;
    const bf16*  pu = xc  + (size_t)c * LCHUNK * DINNER + d;
    const float* pb = bc  + (size_t)c * LCHUNK * 32;        // wave-uniform

#pragma unroll 2
    for (int l = 0; l < LCHUNK; ++l) {
        const float delta = *pd;
        const float u     = b2f(*pu);
        const float du    = delta * u;
        sdelta += delta;
        float4v B0 = *(const float4v*)pb;
        float4v B1 = *(const float4v*)(pb + 4);
        float4v B2 = *(const float4v*)(pb + 8);
        float4v B3 = *(const float4v*)(pb + 12);
#pragma unroll
        for (int i = 0; i < 16; i++) {
            float dA = __expf(delta * Ac[i]);
            float Bi = (i < 4) ? B0[i] : (i < 8) ? B1[i - 4] : (i < 12) ? B2[i - 8] : B3[i - 12];
            h[i] = h[i] * dA + du * Bi;
        }
        pd += DINNER; pu += DINNER; pb += 32;
    }

    float* hp = hend + ((size_t)c * DINNER + d) * DSTATE;
    float* pp = Pbuf + ((size_t)c * DINNER + d) * DSTATE;
#pragma unroll
    for (int q = 0; q < 4; q++) {
        float4v hv, pv;
#pragma unroll
        for (int j = 0; j < 4; j++) {
            hv[j] = h[q * 4 + j];
            pv[j] = __expf(sdelta * Ac[q * 4 + j]);
        }
        *(float4v*)(hp + q * 4) = hv;
        *(float4v*)(pp + q * 4) = pv;
    }
}

// ---- combine: prefix across chunks; unroll-8 batched loads (latency) ----
__global__ __launch_bounds__(256) void scan_combine(
    float* __restrict__ hend, const float* __restrict__ Pbuf)
{
    const int dn = blockIdx.x * 256 + threadIdx.x;
    const size_t STR = (size_t)DINNER * DSTATE;
    float H = 0.f;
    size_t idx = dn;
    for (int c0 = 0; c0 < NCHUNK; c0 += 8) {
        float he[8], pp[8];
#pragma unroll
        for (int j = 0; j < 8; j++) {
            he[j] = hend[idx + (size_t)j * STR];
            pp[j] = Pbuf[idx + (size_t)j * STR];
        }
#pragma unroll
        for (int j = 0; j < 8; j++) {
            hend[idx + (size_t)j * STR] = H;
            H = he[j] + pp[j] * H;
        }
        idx += 8 * STR;
    }
}

// ---- pass 3: 1 lane per d, 16 states, serial y-dot, coalesced z rw ----
__global__ __launch_bounds__(256) void scan_chunk2(
    const float* __restrict__ dlt, const bf16* __restrict__ xc,
    bf16* __restrict__ xz, const float* __restrict__ bc,
    const float* __restrict__ A_log, const float* __restrict__ Dp,
    const float* __restrict__ Hin)
{
    const int d = blockIdx.x * 256 + threadIdx.x;
    const int c = blockIdx.y;

    float Ac[16];
    {
        const float* ap = A_log + d * DSTATE;
#pragma unroll
        for (int i = 0; i < 16; i++) Ac[i] = -__expf(ap[i]);
    }
    const float Dv = Dp[d];

    float h[16];
    {
        const float* hp = Hin + ((size_t)c * DINNER + d) * DSTATE;
#pragma unroll
        for (int q = 0; q < 4; q++) {
            float4v hv = *(const float4v*)(hp + q * 4);
#pragma unroll
            for (int j = 0; j < 4; j++) h[q * 4 + j] = hv[j];
        }
    }

    const float* pd = dlt + (size_t)c * LCHUNK * DINNER + d;
    const bf16*  pu = xc  + (size_t)c * LCHUNK * DINNER + d;
    const float* pb = bc  + (size_t)c * LCHUNK * 32;        // wave-uniform
    bf16*        pz = xz  + (size_t)c * LCHUNK * (2 * DINNER) + DINNER + d;

#pragma unroll 2
    for (int l = 0; l < LCHUNK; ++l) {
        const float delta = *pd;
        const float u     = b2f(*pu);
        const float du    = delta * u;
        float4v B0 = *(const float4v*)pb;
        float4v B1 = *(const float4v*)(pb + 4);
        float4v B2 = *(const float4v*)(pb + 8);
        float4v B3 = *(const float4v*)(pb + 12);
        float4v C0 = *(const float4v*)(pb + 16);
        float4v C1 = *(const float4v*)(pb + 20);
        float4v C2 = *(const float4v*)(pb + 24);
        float4v C3 = *(const float4v*)(pb + 28);
        float yv = 0.f;
#pragma unroll
        for (int i = 0; i < 16; i++) {
            float dA = __expf(delta * Ac[i]);
            float Bi = (i < 4) ? B0[i] : (i < 8) ? B1[i - 4] : (i < 12) ? B2[i - 8] : B3[i - 12];
            float Ci = (i < 4) ? C0[i] : (i < 8) ? C1[i - 4] : (i < 12) ? C2[i - 8] : C3[i - 12];
            h[i] = h[i] * dA + du * Bi;
            yv += h[i] * Ci;
        }
        yv += u * Dv;
        float z = b2f(*pz);
        yv *= fsilu(z);
        *pz = f2b(yv);
        pd += DINNER; pu += DINNER; pb += 32; pz += 2 * DINNER;
    }
}

// ---- serial scan fallback ----
template<typename DT>
__global__ __launch_bounds__(256) void scan_serial(
    const DT* __restrict__ dlt, bf16* __restrict__ xz,
    const bf16* __restrict__ xdbl,
    const float* __restrict__ A_log, const float* __restrict__ Dp)
{
    const int nq = threadIdx.x & 3;
    const int d  = blockIdx.x * 64 + (threadIdx.x >> 2);
    float Ac[4];
#pragma unroll
    for (int i = 0; i < 4; i++)
        Ac[i] = -__expf(A_log[d * DSTATE + nq * 4 + i]);
    const float Dv = Dp[d];
    float h[4] = {0.f, 0.f, 0.f, 0.f};
    for (int l = 0; l < LSEQ; ++l) {
        const float delta = cvtL<DT>(dlt[(size_t)l * DINNER + d]);
        const float u     = b2f(xz[(size_t)l * (2 * DINNER) + d]);
        const uint2 qb = *(const uint2*)(xdbl + (size_t)l * DXP + DTRANK + nq * 4);
        const uint2 qc = *(const uint2*)(xdbl + (size_t)l * DXP + DTRANK + DSTATE + nq * 4);
        float Bv[4] = { bl16(qb.x), bh16(qb.x), bl16(qb.y), bh16(qb.y) };
        float Cv[4] = { bl16(qc.x), bh16(qc.x), bl16(qc.y), bh16(qc.y) };
        const float du = delta * u;
        float yv = 0.f;
#pragma unroll
        for (int i = 0; i < 4; i++) {
            float dA = __expf(delta * Ac[i]);
            h[i] = h[i] * dA + du * Bv[i];
            yv += h[i] * Cv[i];
        }
        yv += __shfl_xor(yv, 1);
        yv += __shfl_xor(yv, 2);
        if (nq == 0) {
            yv += u * Dv;
            bf16* zp = xz + (size_t)l * (2 * DINNER) + DINNER + d;
            float z = b2f(*zp);
            yv *= z / (1.0f + __expf(-z));
            *zp = f2b(yv);
        }
    }
}

extern "C" void kernel_launch(void* const* d_in, const int* in_sizes, int n_in,
                              void* d_out, int out_size, void* d_ws, size_t ws_size,
                              hipStream_t stream)
{
    const float* hs      = (const float*)d_in[0];
    const float* w_in    = (const float*)d_in[1];
    const float* w_conv  = (const float*)d_in[2];
    const float* w_xproj = (const float*)d_in[3];
    const float* w_dt    = (const float*)d_in[4];
    const float *w_out, *b_dt, *A_log, *Dp;
    if (in_sizes[5] == DMODEL * DINNER) {
        w_out = (const float*)d_in[5];
        b_dt  = (const float*)d_in[6];
        A_log = (const float*)d_in[7];
        Dp    = (const float*)d_in[8];
    } else {
        b_dt  = (const float*)d_in[5];
        A_log = (const float*)d_in[6];
        Dp    = (const float*)d_in[7];
        w_out = (const float*)d_in[8];
    }
    float* out = (float*)d_out;

    const size_t SZ_XZ   = (size_t)LSEQ * 2 * DINNER * sizeof(bf16);         // 33.5 MB
    const size_t SZ_XC   = (size_t)LSEQ * DINNER * sizeof(bf16);             // 16.8 MB
    const size_t SZ_XDBL = (size_t)LSEQ * DXP * sizeof(bf16);                //  0.7 MB
    const size_t SZ_DLTF = (size_t)LSEQ * DINNER * sizeof(float);            // 33.5 MB
    const size_t SZ_HP   = (size_t)NCHUNK * DINNER * DSTATE * sizeof(float); //  8.4 MB
    const size_t SZ_BC   = (size_t)LSEQ * 32 * sizeof(float);                // 0.25 MB

    char* p = (char*)d_ws;
    bf16* xz = (bf16*)p; p += SZ_XZ;

    const size_t need_fast = SZ_XZ + SZ_XC + SZ_XDBL + SZ_DLTF + 2 * SZ_HP + SZ_BC;
    const bool fast = ws_size >= need_fast;

    dim3 blk(256);

    if (fast) {
        bf16*  xc   = (bf16*)p;  p += SZ_XC;
        bf16*  xdbl = (bf16*)p;  p += SZ_XDBL;
        char*  hpr  = p;         p += SZ_DLTF;   // dlt fp32 region (written stage 4)
        char*  dreg = p;                          // hend+Pbuf+bc region
        float* dlt  = (float*)hpr;
        float* hend = (float*)dreg;
        float* Pbuf = (float*)(dreg + SZ_HP);
        float* bcb  = (float*)(dreg + 2 * SZ_HP); // written stage 3, read stage 5

        // time-aliased buffers (stream-serial => safe):
        bf16*  w_in_b  = (bf16*)hpr;              // used stage 1; dead after
        float* xp_part = (float*)hpr;             // stage-3 split-K partials (21 MB)
        bf16*  hs_b    = (bf16*)dreg;             // stage 1; dead before stage-5 hend
        bf16*  w_dt_b  = (bf16*)(dreg + (size_t)LSEQ * DMODEL * sizeof(bf16));
                                                  // stage 4; overlaps Pbuf (stage 5) - OK
        bf16*  w_xp_b  = (bf16*)(dreg + (size_t)LSEQ * DMODEL * sizeof(bf16)
                                      + (size_t)DINNER * DTRANK * sizeof(bf16));
                                                  // stage 3; dead before stage-5 Pbuf
        bf16*  w_out_b = (bf16*)xc;               // written stage 6; xc dead by then

        // 0) one fused convert: w_in, hs, w_dt, w_xproj -> bf16
        {
            int n0 = 2 * DINNER * DMODEL, n1 = LSEQ * DMODEL;
            int n2 = DINNER * DTRANK,     n3 = DXP * DINNER;
            cvt4<<<dim3((n0 + n1 + n2 + n3) / 2048), blk, 0, stream>>>(
                w_in, w_in_b, n0, hs, hs_b, n1, w_dt, w_dt_b, n2, w_xproj, w_xp_b, n3);
        }

        // 1) in_proj: dedicated 256x256 pipelined GEMM (2 barriers/K-tile)
        gemm_inproj<<<dim3(256), dim3(512), 0, stream>>>(
            hs_b, DMODEL, w_in_b, DMODEL, xz, 2*DINNER, DMODEL);

        // 2) conv + silu -> xc (512 blocks, 64 l each)
        conv_silu_par<<<dim3(DINNER/256, LSEQ/64), blk, 0, stream>>>(xz, w_conv, xc);

        // 3) x_proj: dedicated 128x160 split-K MFMA kernel -> partials -> reduce
        gemm_xproj<<<dim3(LSEQ/128, KSPLIT), blk, 0, stream>>>(
            xc, DINNER, w_xp_b, DINNER, xp_part);
        reduce_splitk<<<dim3((LSEQ * DXP + 255) / 256), blk, 0, stream>>>(
            xp_part, xdbl, bcb, LSEQ * DXP);

        // 4) dt_proj + softplus -> dlt fp32 (single-stage K=128)
        gemm_dtproj<<<dim3(LSEQ/128, DINNER/128), blk, 0, stream>>>(
            xdbl, w_dt_b, dlt, b_dt);

        // 5) chunk-parallel scan v3 (NCHUNK=32; hend/Pbuf overwrite hs_b/w_dt_b)
        scan_chunk1<<<dim3(DINNER/256, NCHUNK), blk, 0, stream>>>(
            dlt, xc, bcb, A_log, hend, Pbuf);
        scan_combine<<<dim3(DINNER*DSTATE/256), blk, 0, stream>>>(hend, Pbuf);
        scan_chunk2<<<dim3(DINNER/256, NCHUNK), blk, 0, stream>>>(
            dlt, xc, xz, bcb, A_log, Dp, hend);

        // 6) out_proj: single-pass 128x128 pipelined (3-buf, vmcnt(8)), fp32 out
        cvt1<<<dim3((DMODEL*DINNER)/2048), blk, 0, stream>>>(w_out, w_out_b, DMODEL*DINNER);
        gemm_outproj<<<dim3(256), blk, 0, stream>>>(
            xz + DINNER, 2*DINNER, w_out_b, DINNER, out, DMODEL, DINNER);
    } else {
        // fallback tiers: R4 layout (in-place conv + serial scan, fp32-B gemms)
        bf16* xdbl = (bf16*)p; p += SZ_XDBL;
        size_t used = (size_t)(p - (char*)d_ws);
        bool dlt_f32 = (ws_size - used) >= SZ_DLTF;

        gemm_bt<float, bf16, false><<<dim3(LSEQ/64, (2*DINNER)/64), blk, 0, stream>>>(
            hs, DMODEL, w_in, DMODEL, xz, 2*DINNER, LSEQ, 2*DINNER, DMODEL, nullptr);
        conv_silu_inplace<<<dim3(DINNER/256), blk, 0, stream>>>(xz, w_conv);
        gemm_bt<bf16, bf16, false><<<dim3(LSEQ/64, 3), blk, 0, stream>>>(
            xz, 2*DINNER, w_xproj, DINNER, xdbl, DXP, LSEQ, DXP, DINNER, nullptr);
        if (dlt_f32) {
            float* dlt = (float*)p;
            gemm_bt<bf16, float, true><<<dim3(LSEQ/64, DINNER/64), blk, 0, stream>>>(
                xdbl, DXP, w_dt, DTRANK, dlt, DINNER, LSEQ, DINNER, DTRANK, b_dt);
            scan_serial<float><<<dim3(DINNER/64), blk, 0, stream>>>(dlt, xz, xdbl, A_log, Dp);
        } else {
            bf16* dlt = (bf16*)p;
            gemm_bt<bf16, bf16, true><<<dim3(LSEQ/64, DINNER/64), blk, 0, stream>>>(
                xdbl, DXP, w_dt, DTRANK, dlt, DINNER, LSEQ, DINNER, DTRANK, b_dt);
            scan_serial<bf16><<<dim3(DINNER/64), blk, 0, stream>>>(dlt, xz, xdbl, A_log, Dp);
        }
        gemm_bt<bf16, float, false><<<dim3(LSEQ/64, DMODEL/64), blk, 0, stream>>>(
            xz + DINNER, 2*DINNER, w_out, DINNER, out, DMODEL, LSEQ, DMODEL, DINNER, nullptr);
    }
}

// Round 11
// 386.185 us; speedup vs baseline: 1.0498x; 1.0498x over previous
//
#include <hip/hip_runtime.h>
#include <hip/hip_bf16.h>

#define LSEQ 2048
#define DMODEL 2048
#define DINNER 4096
#define DSTATE 16
#define DTRANK 128
#define DCONV 4
#define DXP (DTRANK + 2*DSTATE)   // 160
#define NCHUNK 64
#define LCHUNK (LSEQ / NCHUNK)    // 32
#define KSPLIT 16

using bf16 = __hip_bfloat16;
typedef __attribute__((ext_vector_type(8))) short short8;
typedef __attribute__((ext_vector_type(4))) float float4v;

__device__ __forceinline__ float b2f(bf16 v) { return __bfloat162float(v); }
__device__ __forceinline__ bf16 f2b(float v) { return __float2bfloat16(v); }
__device__ __forceinline__ float bl16(unsigned u) { return __uint_as_float(u << 16); }
__device__ __forceinline__ float bh16(unsigned u) { return __uint_as_float(u & 0xffff0000u); }

__device__ __forceinline__ short f2bs(float v) {
    bf16 b = __float2bfloat16(v);
    union { bf16 b; short s; } u; u.b = b; return u.s;
}

// fast silu: x * sigmoid(x) with v_rcp instead of full-precision divide
__device__ __forceinline__ float fsilu(float x) {
    return x * __builtin_amdgcn_rcpf(1.0f + __expf(-x));
}

__device__ __forceinline__ short8 ld8(const float* p) {
    float4v f0 = *(const float4v*)p;
    float4v f1 = *(const float4v*)(p + 4);
    short8 r;
    r[0] = f2bs(f0[0]); r[1] = f2bs(f0[1]); r[2] = f2bs(f0[2]); r[3] = f2bs(f0[3]);
    r[4] = f2bs(f1[0]); r[5] = f2bs(f1[1]); r[6] = f2bs(f1[2]); r[7] = f2bs(f1[3]);
    return r;
}
__device__ __forceinline__ short8 ld8(const bf16* p) { return *(const short8*)p; }

template<typename CT> __device__ __forceinline__ CT cvtC(float v);
template<> __device__ __forceinline__ bf16  cvtC<bf16>(float v)  { return f2b(v); }
template<> __device__ __forceinline__ float cvtC<float>(float v) { return v; }

template<typename T> __device__ __forceinline__ float cvtL(T v);
template<> __device__ __forceinline__ float cvtL<bf16>(bf16 v)   { return b2f(v); }
template<> __device__ __forceinline__ float cvtL<float>(float v) { return v; }

// async global->LDS, 16 B per lane, dest = wave-uniform base + lane*16
__device__ __forceinline__ void glds16(const bf16* g, void* lds_base) {
    __builtin_amdgcn_global_load_lds(
        (const __attribute__((address_space(1))) void*)g,
        (__attribute__((address_space(3))) void*)lds_base, 16, 0, 0);
}

// ---- fused fp32->bf16 convert of four arrays (each n % 2048 == 0) ----
__global__ __launch_bounds__(256) void cvt4(
    const float* __restrict__ s0, bf16* __restrict__ d0, int n0,
    const float* __restrict__ s1, bf16* __restrict__ d1, int n1,
    const float* __restrict__ s2, bf16* __restrict__ d2, int n2,
    const float* __restrict__ s3, bf16* __restrict__ d3, int n3)
{
    const int b = blockIdx.x;
    const int nb0 = n0 >> 11, nb1 = n1 >> 11, nb2 = n2 >> 11;
    const float* s; bf16* d; int i;
    if (b < nb0)                  { s = s0; d = d0; i = b * 2048; }
    else if (b < nb0 + nb1)       { s = s1; d = d1; i = (b - nb0) * 2048; }
    else if (b < nb0 + nb1 + nb2) { s = s2; d = d2; i = (b - nb0 - nb1) * 2048; }
    else                          { s = s3; d = d3; i = (b - nb0 - nb1 - nb2) * 2048; }
    i += threadIdx.x * 8;
    *(short8*)(d + i) = ld8(s + i);
}

__global__ __launch_bounds__(256) void cvt1(
    const float* __restrict__ src, bf16* __restrict__ dst, int n)
{
    int i = (blockIdx.x * 256 + threadIdx.x) * 8;
    if (i >= n) return;
    *(short8*)(dst + i) = ld8(src + i);
}

// ============================================================================
// 256x256 2-phase/tile pipelined GEMM (in_proj). ONE trailing barrier per
// phase, 2 phases per K-tile. Counted vmcnt, never 0 mid-loop:
//   phase A: (Alo x Blo)+(Alo x Bhi), 32 MFMA; stage (T+1).AHi+BLo+BHi
//   phase B: (Ahi x Bhi)+(Ahi x Blo), 32 MFMA; stage (T+2).ALo
//   end of T.B: in-flight 10 -> vmcnt(2) drains exactly all of tile T+1.
// ============================================================================
#define GBAR  __builtin_amdgcn_s_barrier()
#define VMW2  asm volatile("s_waitcnt vmcnt(2)" ::: "memory")
#define VMW8  asm volatile("s_waitcnt vmcnt(8)" ::: "memory")
#define VMW0  asm volatile("s_waitcnt vmcnt(0)" ::: "memory")

#define LDA8(BASE, RB, AF) do {                                                \
  _Pragma("unroll") for (int mi_ = 0; mi_ < 4; ++mi_)                          \
  _Pragma("unroll") for (int kk_ = 0; kk_ < 2; ++kk_)                          \
    AF[mi_][kk_] = *(const short8*)((BASE) + (((RB) + mi_*16 + t16) << 6)      \
                                    + ((((kk_*4) + quad) ^ sw7) << 3));        \
} while (0)

#define LDB4(BASE, RB, BF) do {                                                \
  _Pragma("unroll") for (int nj_ = 0; nj_ < 2; ++nj_)                          \
  _Pragma("unroll") for (int kk_ = 0; kk_ < 2; ++kk_)                          \
    BF[nj_][kk_] = *(const short8*)((BASE) + (((RB) + nj_*16 + t16) << 6)      \
                                    + ((((kk_*4) + quad) ^ sw7) << 3));        \
} while (0)

#define MM16(AF, BF, MO, NO) do {                                              \
  _Pragma("unroll") for (int kk_ = 0; kk_ < 2; ++kk_)                          \
  _Pragma("unroll") for (int mi_ = 0; mi_ < 4; ++mi_)                          \
  _Pragma("unroll") for (int nj_ = 0; nj_ < 2; ++nj_)                          \
    acc[(MO)+mi_][(NO)+nj_] = __builtin_amdgcn_mfma_f32_16x16x32_bf16(         \
        AF[mi_][kk_], BF[nj_][kk_], acc[(MO)+mi_][(NO)+nj_], 0, 0, 0);         \
} while (0)

#define ST_ALO(tau) do { size_t ko_ = (size_t)(tau) << 6; int bo_ = ((tau)&1) << 15; \
  glds16(sA +       ko_, dA0 + bo_);                                           \
  glds16(sA + oA1 + ko_, dA1 + bo_); } while (0)
#define ST_AHI(tau) do { size_t ko_ = (size_t)(tau) << 6; int bo_ = ((tau)&1) << 15; \
  glds16(sA + oA2 + ko_, dA2 + bo_);                                           \
  glds16(sA + oA3 + ko_, dA3 + bo_); } while (0)
#define ST_BLO(tau) do { size_t ko_ = (size_t)(tau) << 6; int bo_ = ((tau)&1) << 15; \
  glds16(sB +       ko_, dB0 + bo_);                                           \
  glds16(sB + oB1 + ko_, dB1 + bo_); } while (0)
#define ST_BHI(tau) do { size_t ko_ = (size_t)(tau) << 6; int bo_ = ((tau)&1) << 15; \
  glds16(sB + oB2 + ko_, dB2 + bo_);                                           \
  glds16(sB + oB3 + ko_, dB3 + bo_); } while (0)

// one K-tile (2 phases), BI = compile-time buffer index
#define KSTEP(T, BI) do {                                                      \
    const bf16* Ab = As[BI];                                                   \
    const bf16* Bb = Bs[BI];                                                   \
    short8 af[4][2], b0[2][2], b1[2][2];                                       \
    /* phase A: (Alo x Blo)+(Alo x Bhi); stage (T+1).AHi+BLo+BHi */            \
    LDA8(Ab, wm, af);                                                          \
    LDB4(Bb, wn, b0);                                                          \
    LDB4(Bb, wn + 32, b1);                                                     \
    if ((T) + 1 < NT) { ST_AHI((T) + 1); ST_BLO((T) + 1); ST_BHI((T) + 1); }   \
    __builtin_amdgcn_s_setprio(1);                                             \
    MM16(af, b0, 0, 0); MM16(af, b1, 0, 2);                                    \
    __builtin_amdgcn_s_setprio(0); GBAR;                                       \
    /* phase B: (Ahi x Bhi)+(Ahi x Blo); stage (T+2).ALo */                    \
    LDA8(Ab, wm + 64, af);                                                     \
    if ((T) + 2 < NT) ST_ALO((T) + 2);                                         \
    __builtin_amdgcn_s_setprio(1);                                             \
    MM16(af, b1, 4, 2); MM16(af, b0, 4, 0);                                    \
    __builtin_amdgcn_s_setprio(0);                                             \
    if ((T) + 2 < NT) { VMW2; } else { VMW0; }                                 \
    GBAR;                                                                      \
} while (0)

#define GEMM_PRO_COMMON                                                        \
    const int t    = threadIdx.x;                                              \
    const int wave = t >> 6;                                                   \
    const int lane = t & 63;                                                   \
    const int t16  = lane & 15;                                                \
    const int quad = lane >> 4;                                                \
    const int sw7  = t16 & 7;                                                  \
    const int wm   = (wave >> 2) * 128;                                        \
    const int wn   = (wave & 3) * 64;                                          \
    const int lrow  = lane >> 3;                                               \
    const int lseg  = lane & 7;                                                \
    const int segx  = (lseg ^ lrow) * 8;                                       \
    const int bwoff = (wave & 3) * 8 + (wave >> 2) * 64;

#define GEMM_LDS_DSTS                                                          \
    char* dA0 = (char*)&As[0][(  0 + wave * 8) * 64];                          \
    char* dA1 = (char*)&As[0][(128 + wave * 8) * 64];                          \
    char* dA2 = (char*)&As[0][( 64 + wave * 8) * 64];                          \
    char* dA3 = (char*)&As[0][(192 + wave * 8) * 64];                          \
    char* dB0 = (char*)&Bs[0][(  0 + bwoff) * 64];                             \
    char* dB1 = (char*)&Bs[0][(128 + bwoff) * 64];                             \
    char* dB2 = (char*)&Bs[0][( 32 + bwoff) * 64];                             \
    char* dB3 = (char*)&Bs[0][(160 + bwoff) * 64];

// ---- in_proj: M=2048 (8 tiles) x N (32 tiles), grid 256, bf16 C ----
__global__ __launch_bounds__(512, 2) void gemm_inproj(
    const bf16* __restrict__ A, int lda,
    const bf16* __restrict__ B, int ldb,
    bf16* __restrict__ C, int ldc, int K)
{
    __shared__ __align__(16) bf16 As[2][256 * 64];
    __shared__ __align__(16) bf16 Bs[2][256 * 64];
    GEMM_PRO_COMMON
    const int bid = blockIdx.x;
    const int s   = (bid & 7) * (gridDim.x >> 3) + (bid >> 3);
    const int bm0 = (s & 7) << 8;
    const int bn0 = (s >> 3) << 8;

    const bf16* sA = A + (size_t)(bm0 + wave * 8 + lrow) * lda + segx;
    const bf16* sB = B + (size_t)(bn0 + bwoff + lrow) * ldb + segx;
    const size_t oA1 = (size_t)128 * lda, oA2 = (size_t)64 * lda, oA3 = (size_t)192 * lda;
    const size_t oB1 = (size_t)128 * ldb, oB2 = (size_t)32 * ldb, oB3 = (size_t)160 * ldb;
    GEMM_LDS_DSTS

    const int NT = K >> 6;   // must be even, >= 2

    float4v acc[8][4];
#pragma unroll
    for (int i = 0; i < 8; ++i)
#pragma unroll
        for (int j = 0; j < 4; ++j) acc[i][j] = (float4v)(0.0f);

    // prologue: tile0 fully (8 glds) + tile1.ALo (2); drain tile0 -> vmcnt(2)
    ST_ALO(0); ST_AHI(0); ST_BLO(0); ST_BHI(0);
    if (NT > 1) { ST_ALO(1); VMW2; } else { VMW0; }
    GBAR;

    for (int T = 0; T < NT; T += 2) {
        KSTEP(T, 0);
        KSTEP(T + 1, 1);
    }

#pragma unroll
    for (int mi = 0; mi < 8; ++mi) {
#pragma unroll
        for (int nj = 0; nj < 4; ++nj) {
            const int m_base = bm0 + wm + (mi >> 2) * 64 + (mi & 3) * 16 + quad * 4;
            const int n_g    = bn0 + wn + (nj >> 1) * 32 + (nj & 1) * 16 + t16;
#pragma unroll
            for (int r = 0; r < 4; ++r)
                C[(size_t)(m_base + r) * ldc + n_g] = f2b(acc[mi][nj][r]);
        }
    }
}

// ============================================================================
// out_proj: single-pass 128x128-tile PIPELINED GEMM. 256 blocks (1/CU),
// triple-buffered LDS (96 KB), stage T+2 during T, one trailing barrier per
// K-tile, counted vmcnt(8). REQUIRES: NT % 3 == 1 (K=4096 -> NT=64).
// ============================================================================
#define OST(tau, BI) do { size_t ko_ = (size_t)(tau) << 6;                     \
  _Pragma("unroll") for (int g_ = 0; g_ < 4; ++g_) {                           \
    glds16(Ag[g_] + ko_, Ad[g_] + (BI) * 16384);                               \
    glds16(Bg[g_] + ko_, Bd[g_] + (BI) * 16384); } } while (0)

#define OKSTEP(T, BI) do {                                                     \
    const bf16* Ab = &As[BI][0];                                               \
    const bf16* Bb = &Bs[BI][0];                                               \
    short8 a_[4][2], b_[4][2];                                                 \
    _Pragma("unroll") for (int mi_ = 0; mi_ < 4; ++mi_)                        \
    _Pragma("unroll") for (int kk_ = 0; kk_ < 2; ++kk_)                        \
      a_[mi_][kk_] = *(const short8*)(Ab + ((wm + mi_*16 + t16) << 6)          \
                                      + ((((kk_*4) + quad) ^ sw) << 3));       \
    _Pragma("unroll") for (int nj_ = 0; nj_ < 4; ++nj_)                        \
    _Pragma("unroll") for (int kk_ = 0; kk_ < 2; ++kk_)                        \
      b_[nj_][kk_] = *(const short8*)(Bb + ((wn + nj_*16 + t16) << 6)          \
                                      + ((((kk_*4) + quad) ^ sw) << 3));       \
    if ((T) + 2 < NT) OST((T) + 2, ((BI) + 2) % 3);                            \
    __builtin_amdgcn_s_setprio(1);                                             \
    _Pragma("unroll") for (int kk_ = 0; kk_ < 2; ++kk_)                        \
    _Pragma("unroll") for (int mi_ = 0; mi_ < 4; ++mi_)                        \
    _Pragma("unroll") for (int nj_ = 0; nj_ < 4; ++nj_)                        \
      acc[mi_][nj_] = __builtin_amdgcn_mfma_f32_16x16x32_bf16(                 \
          a_[mi_][kk_], b_[nj_][kk_], acc[mi_][nj_], 0, 0, 0);                 \
    __builtin_amdgcn_s_setprio(0);                                             \
    if ((T) + 2 < NT) { VMW8; }                                                \
    else if ((T) + 1 < NT) { VMW0; }                                           \
    GBAR;                                                                      \
} while (0)

__global__ __launch_bounds__(256, 1) void gemm_outproj(
    const bf16* __restrict__ A, int lda,
    const bf16* __restrict__ B, int ldb,
    float* __restrict__ C, int ldc, int K)
{
    __shared__ __align__(16) bf16 As[3][128 * 64];   // 48 KB
    __shared__ __align__(16) bf16 Bs[3][128 * 64];   // 48 KB

    const int t    = threadIdx.x;
    const int wave = t >> 6;
    const int lane = t & 63;
    const int t16  = lane & 15;
    const int quad = lane >> 4;
    const int sw   = t16 & 7;
    const int wm   = (wave >> 1) * 64;
    const int wn   = (wave & 1) * 64;

    // XCD-region swizzle: each XCD owns an 8m x 4n tile region (bijective)
    const int bid = blockIdx.x;
    const int m_t = ((bid & 1) << 3) | ((bid >> 3) & 7);
    const int n_t = (((bid >> 1) & 3) << 2) | ((bid >> 6) & 3);
    const int bm0 = m_t << 7;
    const int bn0 = n_t << 7;

    const int lrow = lane >> 3;
    const int gseg = ((lane & 7) ^ lrow) * 8;

    const bf16* Ag[4]; char* Ad[4];
#pragma unroll
    for (int g = 0; g < 4; g++) {
        int r = wave * 32 + g * 8;
        Ag[g] = A + (size_t)(bm0 + r + lrow) * lda + gseg;
        Ad[g] = (char*)&As[0][0] + r * 128;
    }
    const bf16* Bg[4]; char* Bd[4];
#pragma unroll
    for (int g = 0; g < 4; g++) {
        int r = wave * 32 + g * 8;
        Bg[g] = B + (size_t)(bn0 + r + lrow) * ldb + gseg;
        Bd[g] = (char*)&Bs[0][0] + r * 128;
    }

    const int NT = K >> 6;   // must satisfy NT % 3 == 1, NT >= 4

    float4v acc[4][4];
#pragma unroll
    for (int i = 0; i < 4; i++)
#pragma unroll
        for (int j = 0; j < 4; j++) acc[i][j] = (float4v)(0.0f);

    OST(0, 0);
    OST(1, 1);
    VMW8;
    GBAR;

    for (int T = 0; T + 2 < NT; T += 3) {
        OKSTEP(T, 0);
        OKSTEP(T + 1, 1);
        OKSTEP(T + 2, 2);
    }
    OKSTEP(NT - 1, 0);   // NT % 3 == 1 -> (NT-1) % 3 == 0

#pragma unroll
    for (int mi = 0; mi < 4; mi++) {
#pragma unroll
        for (int nj = 0; nj < 4; nj++) {
            int n_g = bn0 + wn + nj * 16 + t16;
#pragma unroll
            for (int r = 0; r < 4; r++) {
                int m_g = bm0 + wm + mi * 16 + quad * 4 + r;
                C[(size_t)m_g * ldc + n_g] = acc[mi][nj][r];
            }
        }
    }
}

// ============================================================================
// Dedicated x_proj GEMM: M=2048 (16 tiles of 128) x N=160, split-K=16.
// ============================================================================
__global__ __launch_bounds__(256) void gemm_xproj(
    const bf16* __restrict__ A, int lda,      // xc [2048][4096]
    const bf16* __restrict__ B, int ldb,      // w_xproj_b [160][4096]
    float* __restrict__ P)                    // [KSPLIT][2048][160]
{
    __shared__ bf16 As[128][64];              // 16 KB
    __shared__ bf16 Bs[160][64];              // 20 KB

    const int t    = threadIdx.x;
    const int wave = t >> 6;
    const int lane = t & 63;
    const int t16  = lane & 15;
    const int quad = lane >> 4;
    const int wm   = (wave >> 1) * 64;
    const int wn   = (wave & 1) * 80;
    const int bm0  = blockIdx.x * 128;
    const int kbeg = blockIdx.y * (DINNER / KSPLIT);   // 256-wide K slice

    const int lrow = lane >> 3;
    const int gseg = ((lane & 7) ^ lrow) * 8;

    const bf16* Ag[4]; char* Ad[4];
#pragma unroll
    for (int g = 0; g < 4; g++) {
        int r = wave * 32 + g * 8;
        Ag[g] = A + (size_t)(bm0 + r + lrow) * lda + gseg + kbeg;
        Ad[g] = (char*)As + r * 128;
    }
    const bf16* Bg[5]; char* Bd[5];
#pragma unroll
    for (int g = 0; g < 5; g++) {
        int r = wave * 40 + g * 8;
        Bg[g] = B + (size_t)(r + lrow) * ldb + gseg + kbeg;
        Bd[g] = (char*)Bs + r * 128;
    }

    float4v acc[4][5];
#pragma unroll
    for (int i = 0; i < 4; i++)
#pragma unroll
        for (int j = 0; j < 5; j++) acc[i][j] = (float4v)(0.0f);

    const int sw = t16 & 7;

    for (int k0 = 0; k0 < DINNER / KSPLIT; k0 += 64) {
        __syncthreads();
#pragma unroll
        for (int g = 0; g < 4; g++) glds16(Ag[g] + k0, Ad[g]);
#pragma unroll
        for (int g = 0; g < 5; g++) glds16(Bg[g] + k0, Bd[g]);
        __syncthreads();

#pragma unroll
        for (int kk = 0; kk < 2; kk++) {
            const int kso = ((kk * 4 + quad) ^ sw) * 8;
            short8 a[4], b[5];
#pragma unroll
            for (int mi = 0; mi < 4; mi++)
                a[mi] = *(const short8*)(&As[wm + mi * 16 + t16][kso]);
#pragma unroll
            for (int nj = 0; nj < 5; nj++)
                b[nj] = *(const short8*)(&Bs[wn + nj * 16 + t16][kso]);
#pragma unroll
            for (int mi = 0; mi < 4; mi++)
#pragma unroll
                for (int nj = 0; nj < 5; nj++)
                    acc[mi][nj] = __builtin_amdgcn_mfma_f32_16x16x32_bf16(
                        a[mi], b[nj], acc[mi][nj], 0, 0, 0);
        }
    }

    float* Pk = P + (size_t)blockIdx.y * LSEQ * DXP;
#pragma unroll
    for (int mi = 0; mi < 4; mi++) {
#pragma unroll
        for (int nj = 0; nj < 5; nj++) {
            int n_g = wn + nj * 16 + t16;
#pragma unroll
            for (int r = 0; r < 4; r++) {
                int m_g = bm0 + wm + mi * 16 + quad * 4 + r;
                Pk[(size_t)m_g * DXP + n_g] = acc[mi][nj][r];
            }
        }
    }
}

// ============================================================================
// Dedicated dt_proj: single-stage K=128 GEMM + bias + softplus -> fp32.
// Tile 128x128, grid (16,32), 64 KB LDS (2 blocks/CU), ONE barrier pair.
// ============================================================================
__global__ __launch_bounds__(256) void gemm_dtproj(
    const bf16* __restrict__ A,
    const bf16* __restrict__ B,
    float* __restrict__ C,
    const float* __restrict__ bias)
{
    __shared__ __align__(16) bf16 As[128][128];   // 32 KB
    __shared__ __align__(16) bf16 Bs[128][128];   // 32 KB

    const int t    = threadIdx.x;
    const int wave = t >> 6;
    const int lane = t & 63;
    const int t16  = lane & 15;
    const int quad = lane >> 4;
    const int wm   = (wave >> 1) * 64;
    const int wn   = (wave & 1) * 64;
    const int bm0  = blockIdx.x * 128;
    const int bn0  = blockIdx.y * 128;

    // per statement: 256 thr x 16B = 16 rows of 256B; wave covers 4 rows
    const int srow = wave * 4 + (lane >> 4);          // row-in-group 0..15
    const int scol = ((lane & 15) ^ srow) * 8;        // pre-swizzled col (elems)

    // stage all of K=128: 8 A statements + 8 B statements
#pragma unroll
    for (int g = 0; g < 8; g++) {
        glds16(A + (size_t)(bm0 + g * 16 + srow) * DXP + scol,
               (char*)As + (g * 16 + wave * 4) * 256);
        glds16(B + (size_t)(bn0 + g * 16 + srow) * DTRANK + scol,
               (char*)Bs + (g * 16 + wave * 4) * 256);
    }
    VMW0;
    GBAR;

    float4v acc[4][4];
#pragma unroll
    for (int i = 0; i < 4; i++)
#pragma unroll
        for (int j = 0; j < 4; j++) acc[i][j] = (float4v)(0.0f);

#pragma unroll
    for (int kk = 0; kk < 4; kk++) {
        const int kso = ((kk * 4 + quad) ^ t16) * 8;
        short8 a[4], b[4];
#pragma unroll
        for (int mi = 0; mi < 4; mi++)
            a[mi] = *(const short8*)(&As[wm + mi * 16 + t16][kso]);
#pragma unroll
        for (int nj = 0; nj < 4; nj++)
            b[nj] = *(const short8*)(&Bs[wn + nj * 16 + t16][kso]);
#pragma unroll
        for (int mi = 0; mi < 4; mi++)
#pragma unroll
            for (int nj = 0; nj < 4; nj++)
                acc[mi][nj] = __builtin_amdgcn_mfma_f32_16x16x32_bf16(
                    a[mi], b[nj], acc[mi][nj], 0, 0, 0);
    }

#pragma unroll
    for (int mi = 0; mi < 4; mi++) {
#pragma unroll
        for (int nj = 0; nj < 4; nj++) {
            int n_g = bn0 + wn + nj * 16 + t16;
            float bia = bias[n_g];
#pragma unroll
            for (int r = 0; r < 4; r++) {
                int m_g = bm0 + wm + mi * 16 + quad * 4 + r;
                float x = acc[mi][nj][r] + bia;
                float v = (x > 20.0f) ? x : __logf(1.0f + __expf(x));
                C[(size_t)m_g * DINNER + n_g] = v;
            }
        }
    }
}

// ---- guarded 64x64 GEMM (fallback tiers); B is fp32 ----
template<typename AT, typename CT, bool SP>
__global__ __launch_bounds__(256) void gemm_bt(
    const AT* __restrict__ A, int lda,
    const float* __restrict__ B, int ldb,
    CT* __restrict__ C, int ldc,
    int M, int N, int K,
    const float* __restrict__ bias)
{
    __shared__ bf16 As[64][40];
    __shared__ bf16 Bs[64][40];

    const int t    = threadIdx.x;
    const int bm0  = blockIdx.x * 64;
    const int bn0  = blockIdx.y * 64;
    const int row  = t >> 2;
    const int seg  = (t & 3) * 8;
    const int wave = t >> 6;
    const int lane = t & 63;
    const int wm   = (wave >> 1) * 32;
    const int wn   = (wave & 1) * 32;
    const int t16  = lane & 15;
    const int quad = lane >> 4;

    float4v acc[2][2];
#pragma unroll
    for (int i = 0; i < 2; i++)
#pragma unroll
        for (int j = 0; j < 2; j++) acc[i][j] = (float4v)(0.0f);

    const AT*    Aptr = A + (size_t)(bm0 + row) * lda + seg;
    const float* Bptr = B + (size_t)(bn0 + row) * ldb + seg;
    const bool a_ok = (bm0 + row) < M;
    const bool b_ok = (bn0 + row) < N;
    const short8 zero8 = (short8)(0);

    for (int k0 = 0; k0 < K; k0 += 32) {
        short8 av = a_ok ? ld8(Aptr + k0) : zero8;
        short8 bv = b_ok ? ld8(Bptr + k0) : zero8;
        __syncthreads();
        *(short8*)(&As[row][seg]) = av;
        *(short8*)(&Bs[row][seg]) = bv;
        __syncthreads();

        short8 a0 = *(const short8*)(&As[wm + t16][quad * 8]);
        short8 a1 = *(const short8*)(&As[wm + 16 + t16][quad * 8]);
        short8 b0 = *(const short8*)(&Bs[wn + t16][quad * 8]);
        short8 b1 = *(const short8*)(&Bs[wn + 16 + t16][quad * 8]);
        acc[0][0] = __builtin_amdgcn_mfma_f32_16x16x32_bf16(a0, b0, acc[0][0], 0, 0, 0);
        acc[0][1] = __builtin_amdgcn_mfma_f32_16x16x32_bf16(a0, b1, acc[0][1], 0, 0, 0);
        acc[1][0] = __builtin_amdgcn_mfma_f32_16x16x32_bf16(a1, b0, acc[1][0], 0, 0, 0);
        acc[1][1] = __builtin_amdgcn_mfma_f32_16x16x32_bf16(a1, b1, acc[1][1], 0, 0, 0);
    }

#pragma unroll
    for (int i = 0; i < 2; i++) {
#pragma unroll
        for (int j = 0; j < 2; j++) {
            int n_g = bn0 + wn + j * 16 + t16;
            if (n_g >= N) continue;
            float bia = SP ? bias[n_g] : 0.0f;
#pragma unroll
            for (int r = 0; r < 4; r++) {
                int m_g = bm0 + wm + i * 16 + quad * 4 + r;
                if (m_g >= M) continue;
                float v = acc[i][j][r];
                if (SP) {
                    float x = v + bia;
                    v = (x > 20.0f) ? x : log1pf(__expf(x));
                }
                C[(size_t)m_g * ldc + n_g] = cvtC<CT>(v);
            }
        }
    }
}

// ---- sum KS fp32 partials -> bf16 xdbl; also emit fp32 B/C side-buffer ----
// bc layout: [l][32] fp32 : B[0..15], C[0..15]  (256 KB, L2-resident)
__global__ __launch_bounds__(256) void reduce_splitk(
    const float* __restrict__ P, bf16* __restrict__ C, float* __restrict__ bc, int MN)
{
    int i = blockIdx.x * 256 + threadIdx.x;
    if (i >= MN) return;
    float s = 0.f;
#pragma unroll
    for (int ks = 0; ks < KSPLIT; ks++) s += P[(size_t)ks * MN + i];
    C[i] = f2b(s);
    int l = i / DXP;
    int p = i - l * DXP;
    if (p >= DTRANK) bc[l * 32 + (p - DTRANK)] = s;
}

// ---- conv, L-parallel: reads xz (x-half), writes xc; 64 l per block ----
__global__ __launch_bounds__(256) void conv_silu_par(
    const bf16* __restrict__ xz, const float* __restrict__ w, bf16* __restrict__ xc)
{
    const int d  = blockIdx.x * 256 + threadIdx.x;
    const int lc = blockIdx.y * 64;
    const float w0 = w[d * 4 + 0];
    const float w1 = w[d * 4 + 1];
    const float w2 = w[d * 4 + 2];
    const float w3 = w[d * 4 + 3];
    const size_t S = 2 * DINNER;
    const bf16* p = xz + d;
    float xm3 = 0.f, xm2 = 0.f, xm1 = 0.f;
    if (lc >= 3) {
        xm3 = b2f(p[(size_t)(lc - 3) * S]);
        xm2 = b2f(p[(size_t)(lc - 2) * S]);
        xm1 = b2f(p[(size_t)(lc - 1) * S]);
    }
    for (int l = lc; l < lc + 64; ++l) {
        float x0 = b2f(p[(size_t)l * S]);
        float a = w0 * xm3 + w1 * xm2 + w2 * xm1 + w3 * x0;
        xc[(size_t)l * DINNER + d] = f2b(fsilu(a));
        xm3 = xm2; xm2 = xm1; xm1 = x0;
    }
}

// ---- conv, serial in-place fallback ----
__global__ __launch_bounds__(256) void conv_silu_inplace(
    bf16* __restrict__ xz, const float* __restrict__ w)
{
    const int d = blockIdx.x * 256 + threadIdx.x;
    const float w0 = w[d * 4 + 0];
    const float w1 = w[d * 4 + 1];
    const float w2 = w[d * 4 + 2];
    const float w3 = w[d * 4 + 3];
    bf16* p = xz + d;
    const size_t S = 2 * DINNER;
    float xm3 = 0.f, xm2 = 0.f, xm1 = 0.f;
    for (int l = 0; l < LSEQ; l += 4) {
        float x0 = b2f(p[(size_t)(l + 0) * S]);
        float x1 = b2f(p[(size_t)(l + 1) * S]);
        float x2 = b2f(p[(size_t)(l + 2) * S]);
        float x3 = b2f(p[(size_t)(l + 3) * S]);
        float a0 = w0 * xm3 + w1 * xm2 + w2 * xm1 + w3 * x0;
        float a1 = w0 * xm2 + w1 * xm1 + w2 * x0  + w3 * x1;
        float a2 = w0 * xm1 + w1 * x0  + w2 * x1  + w3 * x2;
        float a3 = w0 * x0  + w1 * x1  + w2 * x2  + w3 * x3;
        p[(size_t)(l + 0) * S] = f2b(a0 / (1.0f + __expf(-a0)));
        p[(size_t)(l + 1) * S] = f2b(a1 / (1.0f + __expf(-a1)));
        p[(size_t)(l + 2) * S] = f2b(a2 / (1.0f + __expf(-a2)));
        p[(size_t)(l + 3) * S] = f2b(a3 / (1.0f + __expf(-a3)));
        xm3 = x1; xm2 = x2; xm1 = x3;
    }
}

// ============================================================================
// Chunked scan v3: ONE lane per d, all 16 states in-register. __expf (native
// v_exp path). NCHUNK=64 (4 waves/SIMD - NCHUNK=32 halved occupancy and
// regressed ~16us, R10 post-mortem).
// ============================================================================
__global__ __launch_bounds__(256) void scan_chunk1(
    const float* __restrict__ dlt, const bf16* __restrict__ xc,
    const float* __restrict__ bc, const float* __restrict__ A_log,
    float* __restrict__ hend, float* __restrict__ Pbuf)
{
    const int d = blockIdx.x * 256 + threadIdx.x;
    const int c = blockIdx.y;

    float Ac[16];
    {
        const float* ap = A_log + d * DSTATE;
#pragma unroll
        for (int i = 0; i < 16; i++) Ac[i] = -__expf(ap[i]);
    }

    float h[16];
#pragma unroll
    for (int i = 0; i < 16; i++) h[i] = 0.f;
    float sdelta = 0.f;

    const float* pd = dlt + (size_t)c * LCHUNK * DINNER + d;
    const bf16*  pu = xc  + (size_t)c * LCHUNK * DINNER + d;
    const float* pb = bc  + (size_t)c * LCHUNK * 32;        // wave-uniform

#pragma unroll 2
    for (int l = 0; l < LCHUNK; ++l) {
        const float delta = *pd;
        const float u     = b2f(*pu);
        const float du    = delta * u;
        sdelta += delta;
        float4v B0 = *(const float4v*)pb;
        float4v B1 = *(const float4v*)(pb + 4);
        float4v B2 = *(const float4v*)(pb + 8);
        float4v B3 = *(const float4v*)(pb + 12);
#pragma unroll
        for (int i = 0; i < 16; i++) {
            float dA = __expf(delta * Ac[i]);
            float Bi = (i < 4) ? B0[i] : (i < 8) ? B1[i - 4] : (i < 12) ? B2[i - 8] : B3[i - 12];
            h[i] = h[i] * dA + du * Bi;
        }
        pd += DINNER; pu += DINNER; pb += 32;
    }

    float* hp = hend + ((size_t)c * DINNER + d) * DSTATE;
    float* pp = Pbuf + ((size_t)c * DINNER + d) * DSTATE;
#pragma unroll
    for (int q = 0; q < 4; q++) {
        float4v hv, pv;
#pragma unroll
        for (int j = 0; j < 4; j++) {
            hv[j] = h[q * 4 + j];
            pv[j] = __expf(sdelta * Ac[q * 4 + j]);
        }
        *(float4v*)(hp + q * 4) = hv;
        *(float4v*)(pp + q * 4) = pv;
    }
}

// ---- combine: prefix across chunks; unroll-8 batched loads (latency) ----
__global__ __launch_bounds__(256) void scan_combine(
    float* __restrict__ hend, const float* __restrict__ Pbuf)
{
    const int dn = blockIdx.x * 256 + threadIdx.x;
    const size_t STR = (size_t)DINNER * DSTATE;
    float H = 0.f;
    size_t idx = dn;
    for (int c0 = 0; c0 < NCHUNK; c0 += 8) {
        float he[8], pp[8];
#pragma unroll
        for (int j = 0; j < 8; j++) {
            he[j] = hend[idx + (size_t)j * STR];
            pp[j] = Pbuf[idx + (size_t)j * STR];
        }
#pragma unroll
        for (int j = 0; j < 8; j++) {
            hend[idx + (size_t)j * STR] = H;
            H = he[j] + pp[j] * H;
        }
        idx += 8 * STR;
    }
}

// ---- pass 3: 1 lane per d, 16 states, serial y-dot, coalesced z rw ----
__global__ __launch_bounds__(256) void scan_chunk2(
    const float* __restrict__ dlt, const bf16* __restrict__ xc,
    bf16* __restrict__ xz, const float* __restrict__ bc,
    const float* __restrict__ A_log, const float* __restrict__ Dp,
    const float* __restrict__ Hin)
{
    const int d = blockIdx.x * 256 + threadIdx.x;
    const int c = blockIdx.y;

    float Ac[16];
    {
        const float* ap = A_log + d * DSTATE;
#pragma unroll
        for (int i = 0; i < 16; i++) Ac[i] = -__expf(ap[i]);
    }
    const float Dv = Dp[d];

    float h[16];
    {
        const float* hp = Hin + ((size_t)c * DINNER + d) * DSTATE;
#pragma unroll
        for (int q = 0; q < 4; q++) {
            float4v hv = *(const float4v*)(hp + q * 4);
#pragma unroll
            for (int j = 0; j < 4; j++) h[q * 4 + j] = hv[j];
        }
    }

    const float* pd = dlt + (size_t)c * LCHUNK * DINNER + d;
    const bf16*  pu = xc  + (size_t)c * LCHUNK * DINNER + d;
    const float* pb = bc  + (size_t)c * LCHUNK * 32;        // wave-uniform
    bf16*        pz = xz  + (size_t)c * LCHUNK * (2 * DINNER) + DINNER + d;

#pragma unroll 2
    for (int l = 0; l < LCHUNK; ++l) {
        const float delta = *pd;
        const float u     = b2f(*pu);
        const float du    = delta * u;
        float4v B0 = *(const float4v*)pb;
        float4v B1 = *(const float4v*)(pb + 4);
        float4v B2 = *(const float4v*)(pb + 8);
        float4v B3 = *(const float4v*)(pb + 12);
        float4v C0 = *(const float4v*)(pb + 16);
        float4v C1 = *(const float4v*)(pb + 20);
        float4v C2 = *(const float4v*)(pb + 24);
        float4v C3 = *(const float4v*)(pb + 28);
        float yv = 0.f;
#pragma unroll
        for (int i = 0; i < 16; i++) {
            float dA = __expf(delta * Ac[i]);
            float Bi = (i < 4) ? B0[i] : (i < 8) ? B1[i - 4] : (i < 12) ? B2[i - 8] : B3[i - 12];
            float Ci = (i < 4) ? C0[i] : (i < 8) ? C1[i - 4] : (i < 12) ? C2[i - 8] : C3[i - 12];
            h[i] = h[i] * dA + du * Bi;
            yv += h[i] * Ci;
        }
        yv += u * Dv;
        float z = b2f(*pz);
        yv *= fsilu(z);
        *pz = f2b(yv);
        pd += DINNER; pu += DINNER; pb += 32; pz += 2 * DINNER;
    }
}

// ---- serial scan fallback ----
template<typename DT>
__global__ __launch_bounds__(256) void scan_serial(
    const DT* __restrict__ dlt, bf16* __restrict__ xz,
    const bf16* __restrict__ xdbl,
    const float* __restrict__ A_log, const float* __restrict__ Dp)
{
    const int nq = threadIdx.x & 3;
    const int d  = blockIdx.x * 64 + (threadIdx.x >> 2);
    float Ac[4];
#pragma unroll
    for (int i = 0; i < 4; i++)
        Ac[i] = -__expf(A_log[d * DSTATE + nq * 4 + i]);
    const float Dv = Dp[d];
    float h[4] = {0.f, 0.f, 0.f, 0.f};
    for (int l = 0; l < LSEQ; ++l) {
        const float delta = cvtL<DT>(dlt[(size_t)l * DINNER + d]);
        const float u     = b2f(xz[(size_t)l * (2 * DINNER) + d]);
        const uint2 qb = *(const uint2*)(xdbl + (size_t)l * DXP + DTRANK + nq * 4);
        const uint2 qc = *(const uint2*)(xdbl + (size_t)l * DXP + DTRANK + DSTATE + nq * 4);
        float Bv[4] = { bl16(qb.x), bh16(qb.x), bl16(qb.y), bh16(qb.y) };
        float Cv[4] = { bl16(qc.x), bh16(qc.x), bl16(qc.y), bh16(qc.y) };
        const float du = delta * u;
        float yv = 0.f;
#pragma unroll
        for (int i = 0; i < 4; i++) {
            float dA = __expf(delta * Ac[i]);
            h[i] = h[i] * dA + du * Bv[i];
            yv += h[i] * Cv[i];
        }
        yv += __shfl_xor(yv, 1);
        yv += __shfl_xor(yv, 2);
        if (nq == 0) {
            yv += u * Dv;
            bf16* zp = xz + (size_t)l * (2 * DINNER) + DINNER + d;
            float z = b2f(*zp);
            yv *= z / (1.0f + __expf(-z));
            *zp = f2b(yv);
        }
    }
}

extern "C" void kernel_launch(void* const* d_in, const int* in_sizes, int n_in,
                              void* d_out, int out_size, void* d_ws, size_t ws_size,
                              hipStream_t stream)
{
    const float* hs      = (const float*)d_in[0];
    const float* w_in    = (const float*)d_in[1];
    const float* w_conv  = (const float*)d_in[2];
    const float* w_xproj = (const float*)d_in[3];
    const float* w_dt    = (const float*)d_in[4];
    const float *w_out, *b_dt, *A_log, *Dp;
    if (in_sizes[5] == DMODEL * DINNER) {
        w_out = (const float*)d_in[5];
        b_dt  = (const float*)d_in[6];
        A_log = (const float*)d_in[7];
        Dp    = (const float*)d_in[8];
    } else {
        b_dt  = (const float*)d_in[5];
        A_log = (const float*)d_in[6];
        Dp    = (const float*)d_in[7];
        w_out = (const float*)d_in[8];
    }
    float* out = (float*)d_out;

    const size_t SZ_XZ   = (size_t)LSEQ * 2 * DINNER * sizeof(bf16);         // 33.5 MB
    const size_t SZ_XC   = (size_t)LSEQ * DINNER * sizeof(bf16);             // 16.8 MB
    const size_t SZ_XDBL = (size_t)LSEQ * DXP * sizeof(bf16);                //  0.7 MB
    const size_t SZ_DLTF = (size_t)LSEQ * DINNER * sizeof(float);            // 33.5 MB
    const size_t SZ_HP   = (size_t)NCHUNK * DINNER * DSTATE * sizeof(float); // 16.8 MB
    const size_t SZ_BC   = (size_t)LSEQ * 32 * sizeof(float);                // 0.25 MB

    char* p = (char*)d_ws;
    bf16* xz = (bf16*)p; p += SZ_XZ;

    const size_t need_fast = SZ_XZ + SZ_XC + SZ_XDBL + SZ_DLTF + 2 * SZ_HP + SZ_BC;
    const bool fast = ws_size >= need_fast;

    dim3 blk(256);

    if (fast) {
        bf16*  xc   = (bf16*)p;  p += SZ_XC;
        bf16*  xdbl = (bf16*)p;  p += SZ_XDBL;
        char*  hpr  = p;         p += SZ_DLTF;   // dlt fp32 region (written stage 4)
        char*  dreg = p;                          // hend+Pbuf+bc region
        float* dlt  = (float*)hpr;
        float* hend = (float*)dreg;
        float* Pbuf = (float*)(dreg + SZ_HP);
        float* bcb  = (float*)(dreg + 2 * SZ_HP); // written stage 3, read stage 5

        // time-aliased buffers (stream-serial => safe):
        bf16*  w_in_b  = (bf16*)hpr;              // used stage 1; dead after
        float* xp_part = (float*)hpr;             // stage-3 split-K partials (21 MB)
        bf16*  hs_b    = (bf16*)dreg;             // stage 1; dead before stage-5 hend
        bf16*  w_dt_b  = (bf16*)(dreg + (size_t)LSEQ * DMODEL * sizeof(bf16));
                                                  // stage 4; dead before stage-5 writes
        bf16*  w_xp_b  = (bf16*)(dreg + (size_t)LSEQ * DMODEL * sizeof(bf16)
                                      + (size_t)DINNER * DTRANK * sizeof(bf16));
                                                  // stage 3; dead before stage-5 writes
        bf16*  w_out_b = (bf16*)xc;               // written stage 6; xc dead by then

        // 0) one fused convert: w_in, hs, w_dt, w_xproj -> bf16
        {
            int n0 = 2 * DINNER * DMODEL, n1 = LSEQ * DMODEL;
            int n2 = DINNER * DTRANK,     n3 = DXP * DINNER;
            cvt4<<<dim3((n0 + n1 + n2 + n3) / 2048), blk, 0, stream>>>(
                w_in, w_in_b, n0, hs, hs_b, n1, w_dt, w_dt_b, n2, w_xproj, w_xp_b, n3);
        }

        // 1) in_proj: dedicated 256x256 pipelined GEMM (2 barriers/K-tile)
        gemm_inproj<<<dim3(256), dim3(512), 0, stream>>>(
            hs_b, DMODEL, w_in_b, DMODEL, xz, 2*DINNER, DMODEL);

        // 2) conv + silu -> xc (512 blocks, 64 l each)
        conv_silu_par<<<dim3(DINNER/256, LSEQ/64), blk, 0, stream>>>(xz, w_conv, xc);

        // 3) x_proj: dedicated 128x160 split-K MFMA kernel -> partials -> reduce
        gemm_xproj<<<dim3(LSEQ/128, KSPLIT), blk, 0, stream>>>(
            xc, DINNER, w_xp_b, DINNER, xp_part);
        reduce_splitk<<<dim3((LSEQ * DXP + 255) / 256), blk, 0, stream>>>(
            xp_part, xdbl, bcb, LSEQ * DXP);

        // 4) dt_proj + softplus -> dlt fp32 (single-stage K=128)
        gemm_dtproj<<<dim3(LSEQ/128, DINNER/128), blk, 0, stream>>>(
            xdbl, w_dt_b, dlt, b_dt);

        // 5) chunk-parallel scan v3 (NCHUNK=64)
        scan_chunk1<<<dim3(DINNER/256, NCHUNK), blk, 0, stream>>>(
            dlt, xc, bcb, A_log, hend, Pbuf);
        scan_combine<<<dim3(DINNER*DSTATE/256), blk, 0, stream>>>(hend, Pbuf);
        scan_chunk2<<<dim3(DINNER/256, NCHUNK), blk, 0, stream>>>(
            dlt, xc, xz, bcb, A_log, Dp, hend);

        // 6) out_proj: single-pass 128x128 pipelined (3-buf, vmcnt(8)), fp32 out
        cvt1<<<dim3((DMODEL*DINNER)/2048), blk, 0, stream>>>(w_out, w_out_b, DMODEL*DINNER);
        gemm_outproj<<<dim3(256), blk, 0, stream>>>(
            xz + DINNER, 2*DINNER, w_out_b, DINNER, out, DMODEL, DINNER);
    } else {
        // fallback tiers: R4 layout (in-place conv + serial scan, fp32-B gemms)
        bf16* xdbl = (bf16*)p; p += SZ_XDBL;
        size_t used = (size_t)(p - (char*)d_ws);
        bool dlt_f32 = (ws_size - used) >= SZ_DLTF;

        gemm_bt<float, bf16, false><<<dim3(LSEQ/64, (2*DINNER)/64), blk, 0, stream>>>(
            hs, DMODEL, w_in, DMODEL, xz, 2*DINNER, LSEQ, 2*DINNER, DMODEL, nullptr);
        conv_silu_inplace<<<dim3(DINNER/256), blk, 0, stream>>>(xz, w_conv);
        gemm_bt<bf16, bf16, false><<<dim3(LSEQ/64, 3), blk, 0, stream>>>(
            xz, 2*DINNER, w_xproj, DINNER, xdbl, DXP, LSEQ, DXP, DINNER, nullptr);
        if (dlt_f32) {
            float* dlt = (float*)p;
            gemm_bt<bf16, float, true><<<dim3(LSEQ/64, DINNER/64), blk, 0, stream>>>(
                xdbl, DXP, w_dt, DTRANK, dlt, DINNER, LSEQ, DINNER, DTRANK, b_dt);
            scan_serial<float><<<dim3(DINNER/64), blk, 0, stream>>>(dlt, xz, xdbl, A_log, Dp);
        } else {
            bf16* dlt = (bf16*)p;
            gemm_bt<bf16, bf16, true><<<dim3(LSEQ/64, DINNER/64), blk, 0, stream>>>(
                xdbl, DXP, w_dt, DTRANK, dlt, DINNER, LSEQ, DINNER, DTRANK, b_dt);
            scan_serial<bf16><<<dim3(DINNER/64), blk, 0, stream>>>(dlt, xz, xdbl, A_log, Dp);
        }
        gemm_bt<bf16, float, false><<<dim3(LSEQ/64, DMODEL/64), blk, 0, stream>>>(
            xz + DINNER, 2*DINNER, w_out, DINNER, out, DMODEL, LSEQ, DMODEL, DINNER, nullptr);
    }
}